// Round 7
// baseline (190.074 us; speedup 1.0000x reference)
//
#include <hip/hip_runtime.h>
#include <hip/hip_fp16.h>

// Problem geometry (fixed by reference)
#define WINS 7
#define H 160
#define W 160
#define DD 96
#define HO 154          // H - WINS + 1
#define WO 154
#define DOUT 90
#define CSTRIDE (H*W*DD)   // per-(b,c) channel stride

// Tile: 8x8x24 outputs, all 4 classes sequentially per block.
#define TH 8
#define TW 8
#define TD 24
#define IH 14            // TH + WINS - 1
#define IW 14
#define NCOL (IH * IW)   // 196
#define IDS 32           // staged halfs per column (4 x uint4, 16B aligned)
#define NDP 15           // dd-pairs per column
#define SAS 30           // sA dd-stride in halfs; layout [wo][ih][dd]
#define HTILES 20
#define WTILES 20
#define DTILES 4

// R6 structure: wave-owns-dp fusion.
//  - Thread map for A/B: t = dp*16 + r (dp = t>>4, r = t&15). A item = (ih=r,
//    dp), B item = (wo=r&7, ho0=(r>>3)*4, dp). B(dp) reads sA only at its own
//    dp, written by A lanes of the SAME 16-lane group (groups never straddle
//    a wave) -> A->B needs NO barrier (lockstep wave64 + in-order DS pipe +
//    compiler preserves aliasing program order).
//  - vs and sb are SEPARATE arrays (A reads vs concurrent with B writing
//    sb -> a union would race). C reads sb only; staging writes vs only ->
//    no barrier after C either. 2 barriers/class (was 4).
//  - sb = AoS 16B slots (3 half2 + pad): C 6xb128 (was 18xb32), B-writes
//    4xb128 (was 12xb32) -> big LDS-issue reduction (LDS pipe was ~75%
//    issue-occupied by the m134 cost model).
//  - sA relaid [wo][ih][dd]: under the new lane order, A-writes and B-reads
//    are <=2-way (free), A's vs reads fully conflict-free (consecutive
//    lanes differ in ih = the swizzle axis).
//  - Staging (vs write + prefetch issue) moved after bar2, overlapping C.
// LDS: vs 12,544 + sA 20,160 + sb 15,360 + wsum 16 = 48,080 -> 48,128
// -> 3 blocks/CU (measured residency was only ~2.5 blocks at the 5 cap).

struct alignas(8) Half4 { __half x, y, z, w; };

static __device__ __forceinline__ __half2 u2h(unsigned int a) {
    __half2 r; __builtin_memcpy(&r, &a, 4); return r;
}
static __device__ __forceinline__ unsigned int h2u(__half2 v) {
    unsigned int r; __builtin_memcpy(&r, &v, 4); return r;
}
// p = max(v,0) per half; m = (sign clear) ? 1.0h : 0.0h per half.
static __device__ __forceinline__ void pmask(__half2 v, __half2& p, __half2& m) {
    const unsigned int bits = h2u(v);
    const unsigned int neg  = bits & 0x80008000u;
    const unsigned int full = (neg >> 15) * 0xFFFFu;          // 0xFFFF where negative
    p = u2h(bits & ~full);
    m = u2h(((~bits >> 15) & 0x00010001u) * 0x3C00u);         // 1.0h where sign clear
}

__device__ __forceinline__ float sval(float c0, float c1, float c2) {
    // c0=S_m, c1=S_tm, c2=S_t2m over the 343-voxel window; t = m?sigmoid:0.5
    const float S_t  = c1 + 0.5f  * (343.0f - c0);
    const float S_t2 = c2 + 0.25f * (343.0f - c0);
    const float inv  = 1.0f / 343.0f;
    const float ux   = S_t  * inv;
    const float uy   = c0   * inv;
    const float uxx  = S_t2 * inv;
    const float uxy  = c1   * inv;
    const float covn = 49.0f / 48.0f;   // WIN^2/(WIN^2-1)
    const float cc   = 0.00045f;        // (0.03*data_range)^2/2, data_range==1
    const float vx  = covn * (uxx - ux * ux);
    const float vy  = covn * (uy  - uy * uy);
    const float vxy = covn * (uxy - ux * uy);
    return (vxy + cc) * __builtin_amdgcn_rcpf(vx * vy + cc);   // den >= ~3e-4
}

// Pre-pass: v = (y==c ? +sigmoid(x) : -sigmoid(x)) as f16, one value per
// (channel, voxel). Also zeroes acc (replaces the hipMemsetAsync dispatch).
__global__ __launch_bounds__(256)
void sigmoid_prepass(const float* __restrict__ x,
                     const int* __restrict__ y,
                     __half* __restrict__ xs,
                     double* __restrict__ acc) {
    if (blockIdx.x == 0 && blockIdx.y == 0 && threadIdx.x == 0) acc[0] = 0.0;
    const int b  = blockIdx.y;
    const int qv = blockIdx.x * 256 + threadIdx.x;    // 0..614399
    const int off = 4 * qv;
    const int4 yv = *(const int4*)(y + (size_t)b * CSTRIDE + off);
#pragma unroll
    for (int c = 0; c < 4; c++) {
        const size_t xo = ((size_t)(b * 4 + c)) * CSTRIDE + off;
        const float4 xv = *(const float4*)(x + xo);
        const float s0 = 1.0f / (1.0f + __expf(-xv.x));
        const float s1 = 1.0f / (1.0f + __expf(-xv.y));
        const float s2 = 1.0f / (1.0f + __expf(-xv.z));
        const float s3 = 1.0f / (1.0f + __expf(-xv.w));
        Half4 hv;
        hv.x = __float2half((yv.x == c) ? s0 : -s0);
        hv.y = __float2half((yv.y == c) ? s1 : -s1);
        hv.z = __float2half((yv.z == c) ? s2 : -s2);
        hv.w = __float2half((yv.w == c) ? s3 : -s3);
        *(Half4*)(xs + xo) = hv;
    }
}

// 3 blocks/CU (LDS-capped); min 3 waves/EU gives the allocator room.
template <bool PRE>
__global__ __launch_bounds__(256, 3)
void structure_loss_main(const float* __restrict__ x,
                         const int* __restrict__ y,
                         const __half* __restrict__ xs,
                         double* __restrict__ acc) {
    // staged +/- sigma, f16, pair-swizzled (R4 layout). 12,544 B
    __shared__ uint4 vs4[NCOL * 4];
    // W-window sums, f16 SoA planes [wo][ih][dd]: 3 * 8*14*30*2 = 20,160 B
    __shared__ __half sA0p[TW * IH * SAS];
    __shared__ __half sA1p[TW * IH * SAS];
    __shared__ __half sA2p[TW * IH * SAS];
    // H-window sums, AoS 16B slots [col=ho*8+wo][pair]{b0,b1,b2,pad}: 15,360 B
    __shared__ uint4 sb4[64 * NDP];
    __shared__ unsigned int yb[PRE ? 1 : NCOL * 2];   // fallback only
    __shared__ float wsum[4];

    const int dt = blockIdx.x;                 // 0..3
    const int wt = blockIdx.y;                 // 0..19
    const int z  = blockIdx.z;                 // 0..39 = b*HTILES + ht
    const int b  = z / HTILES;
    const int ht = z - b * HTILES;

    const int h0 = ht * TH, w0 = wt * TW;
    const int d0 = dt * TD;                          // output base: 0,24,48,72
    const int dstage = (dt == DTILES - 1) ? 64 : d0; // staged base (16B align)
    const int doff = d0 - dstage;                    // 0 or 8 (uniform)
    const int odmax = min(TD, DOUT - d0);            // 24,24,24,18
    const int* yc = y + (size_t)b * (size_t)CSTRIDE;
    const int t = threadIdx.x;

    // ---- Hoisted per-thread staging descriptors (PRE) ----
    int gof0 = 0, gof1 = 0, gof2 = 0, gof3 = -1;
    int lof0 = 0, lof1 = 0, lof2 = 0, lof3 = 0;
    uint4 pf0, pf1, pf2, pf3;
    if (PRE) {
#pragma unroll
        for (int k = 0; k < 4; k++) {
            const int i = t + 256 * k;
            if (i < NCOL * 4) {
                const int col = i >> 2, q = i & 3;
                const int ih = col / IW, iw = col - ih * IW;
                const int h = min(h0 + ih, H - 1);
                const int w = min(w0 + iw, W - 1);
                const int go = (h * W + w) * DD + dstage + 8 * q;
                const int g  = ((ih & 1) << 2) | ((ih >> 1) & 3);
                const int cp = ((col & 1) << 2) | q;
                const int lo = ((col >> 1) << 7) | ((cp ^ g) << 4);
                if (k == 0) { gof0 = go; lof0 = lo; }
                else if (k == 1) { gof1 = go; lof1 = lo; }
                else if (k == 2) { gof2 = go; lof2 = lo; }
                else { gof3 = go; lof3 = lo; }
            }
        }
    }

    // ---- Hoisted class-invariant role math ----
    // A/B wave-owns-dp map: dp = t>>4, r = t&15.
    const int  dpAB = t >> 4;                 // 0..15 (15 used)
    const int  r16  = t & 15;
    const bool actAB = (dpAB < NDP);          // t < 240
    const bool actA  = actAB && (r16 < IH);
    const int  ihA  = r16;
    const int  sA_  = min(doff + 2 * dpAB, IDS - 2);
    const int  gA   = ((ihA & 1) << 2) | ((ihA >> 1) & 3);
    const int  baseE = ihA * (7 * 128) + (((sA_ >> 3) ^ gA) << 4) + ((2 * sA_) & 15);
    const int  oA0  = ihA * SAS + 2 * dpAB;              // wo-stride IH*SAS
    // B role:
    const int  woB  = r16 & 7, ho0B = (r16 >> 3) * 4;    // 0 or 4
    const int  idxB0 = (woB * IH + ho0B) * SAS + 2 * dpAB;   // k-stride SAS
    const int  sbB0  = (ho0B * 8 + woB) * NDP + dpAB;        // k-stride 120
    // C role:
    const int  dqC  = t & 3, woC = (t >> 2) & 7, hoC = t >> 5;
    const bool actC = (h0 + hoC < HO) && (w0 + woC < WO);
    const int  slotC = (hoC * 8 + woC) * NDP + 3 * dqC;

    // ---- Fallback staging lambda (compute sigmoid from x, fuse y) ----
    auto stageF = [&](int cc) {
        const float* xc = x + ((size_t)b * 4 + cc) * (size_t)CSTRIDE;
#pragma unroll
        for (int k = 0; k < 7; k++) {
            const int i = t + 256 * k;
            if (i < NCOL * 8) {
                const int col = i >> 3, q = i & 7;
                const int ih = col / IW, iw = col - ih * IW;
                const int h = min(h0 + ih, H - 1);
                const int w = min(w0 + iw, W - 1);
                const int dbase = dstage + 4 * q;   // always in-bounds
                const float4 xv = *(const float4*)(xc + (h * W + w) * DD + dbase);
                const unsigned int pk = yb[col * 2 + (q >> 2)] >> (8 * (q & 3));
                const float s0 = 1.0f / (1.0f + __expf(-xv.x));
                const float s1 = 1.0f / (1.0f + __expf(-xv.y));
                const float s2 = 1.0f / (1.0f + __expf(-xv.z));
                const float s3 = 1.0f / (1.0f + __expf(-xv.w));
                Half4 hv;
                hv.x = __float2half(((int)((pk >> 0) & 3u) == cc) ? s0 : -s0);
                hv.y = __float2half(((int)((pk >> 2) & 3u) == cc) ? s1 : -s1);
                hv.z = __float2half(((int)((pk >> 4) & 3u) == cc) ? s2 : -s2);
                hv.w = __float2half(((int)((pk >> 6) & 3u) == cc) ? s3 : -s3);
                const int g  = ((ih & 1) << 2) | ((ih >> 1) & 3);
                const int cp = ((col & 1) << 2) | (q >> 1);
                const int lofs = ((col >> 1) << 7) | ((cp ^ g) << 4) | ((q & 1) << 3);
                *(Half4*)((char*)vs4 + lofs) = hv;
            }
        }
    };

    if (!PRE) {
        // ---- stage y tile 2-bit packed, then class-0 x staging ----
        for (int i = t; i < NCOL * 2; i += 256) {
            const int col = i >> 1, hf = i & 1;
            const int ih = col / IW, iw = col - ih * IW;
            const int h = min(h0 + ih, H - 1);
            const int w = min(w0 + iw, W - 1);
            const size_t cb = (size_t)(h * W + w) * DD;
            const int dstart = dstage + 16 * hf;     // always in-bounds (<=80)
            unsigned int pk = 0u;
#pragma unroll
            for (int j3 = 0; j3 < 4; j3++) {
                const int4 yv = *(const int4*)(yc + cb + dstart + 4 * j3);
                pk |= (unsigned)(yv.x & 3) << (2 * (4 * j3 + 0));
                pk |= (unsigned)(yv.y & 3) << (2 * (4 * j3 + 1));
                pk |= (unsigned)(yv.z & 3) << (2 * (4 * j3 + 2));
                pk |= (unsigned)(yv.w & 3) << (2 * (4 * j3 + 3));
            }
            yb[i] = pk;
        }
        __syncthreads();           // yb ready for stageF
        stageF(0);
    } else {
        // ---- PRE prologue: load class 0, write vs(0), issue class-1 load ----
        const __half* xc0 = xs + ((size_t)b * 4) * (size_t)CSTRIDE;
        pf0 = *(const uint4*)(xc0 + gof0);
        pf1 = *(const uint4*)(xc0 + gof1);
        pf2 = *(const uint4*)(xc0 + gof2);
        if (gof3 >= 0) pf3 = *(const uint4*)(xc0 + gof3);
        *(uint4*)((char*)vs4 + lof0) = pf0;
        *(uint4*)((char*)vs4 + lof1) = pf1;
        *(uint4*)((char*)vs4 + lof2) = pf2;
        if (gof3 >= 0) *(uint4*)((char*)vs4 + lof3) = pf3;
        const __half* xc1 = xc0 + CSTRIDE;
        pf0 = *(const uint4*)(xc1 + gof0);
        pf1 = *(const uint4*)(xc1 + gof1);
        pf2 = *(const uint4*)(xc1 + gof2);
        if (gof3 >= 0) pf3 = *(const uint4*)(xc1 + gof3);
    }

    float lsum = 0.f;

    for (int cl = 0; cl < 4; cl++) {
        __syncthreads();   // bar1: vs(cl) ready; sb(cl-1) reads retired

        // ---- Phase A: W-window, packed f16. One (ih,dp) item per thread ----
        if (actA) {
            const __half2 z2 = __float2half2_rn(0.f);
            __half2 v2[IW];
#pragma unroll
            for (int iw = 0; iw < IW; iw++) {
                const int ad = ((iw & 1) ? (baseE ^ 64) : baseE) + (iw >> 1) * 128;
                v2[iw] = *(const __half2*)((const char*)vs4 + ad);
            }
            __half2 sm = z2, sp = z2, sq = z2;
#pragma unroll
            for (int iw = 0; iw < WINS; iw++) {
                __half2 p, m;
                pmask(v2[iw], p, m);
                sm = __hadd2(sm, m);
                sp = __hadd2(sp, p);
                sq = __hfma2(p, v2[iw], sq);
            }
            int o = oA0;
            *(__half2*)&sA0p[o] = sm;
            *(__half2*)&sA1p[o] = sp;
            *(__half2*)&sA2p[o] = sq;
#pragma unroll
            for (int wo = 1; wo < TW; wo++) {
                const __half2 a = v2[wo + 6], bb = v2[wo - 1];
                __half2 pa, ma, pb, mb;
                pmask(a, pa, ma);
                pmask(bb, pb, mb);
                sm = __hadd2(sm, __hsub2(ma, mb));
                sp = __hadd2(sp, __hsub2(pa, pb));
                sq = __hadd2(sq, __hsub2(__hmul2(pa, a), __hmul2(pb, bb)));
                o += IH * SAS;
                *(__half2*)&sA0p[o] = sm;
                *(__half2*)&sA1p[o] = sp;
                *(__half2*)&sA2p[o] = sq;
            }
        }

        // ---- Phase B (NO barrier: dp-local, same-wave dep on sA) ----
        if (actAB) {
            __half2 a0[10], a1[10], a2[10];
#pragma unroll
            for (int k = 0; k < 10; k++) {
                const int idx = idxB0 + k * SAS;
                a0[k] = *(const __half2*)&sA0p[idx];
                a1[k] = *(const __half2*)&sA1p[idx];
                a2[k] = *(const __half2*)&sA2p[idx];
            }
            __half2 s0 = a0[0], s1 = a1[0], s2 = a2[0];
#pragma unroll
            for (int k = 1; k < WINS; k++) {
                s0 = __hadd2(s0, a0[k]);
                s1 = __hadd2(s1, a1[k]);
                s2 = __hadd2(s2, a2[k]);
            }
            int o = sbB0;
            sb4[o] = make_uint4(h2u(s0), h2u(s1), h2u(s2), 0u);
#pragma unroll
            for (int k = 1; k < 4; k++) {
                s0 = __hadd2(s0, __hsub2(a0[k + 6], a0[k - 1]));
                s1 = __hadd2(s1, __hsub2(a1[k + 6], a1[k - 1]));
                s2 = __hadd2(s2, __hsub2(a2[k + 6], a2[k - 1]));
                o += TW * NDP;
                sb4[o] = make_uint4(h2u(s0), h2u(s1), h2u(s2), 0u);
            }
        }
        __syncthreads();   // bar2: sb ready; vs free (A reads done)

        // ---- Staging for class cl+1 overlaps Phase C ----
        if (PRE) {
            if (cl < 3) {
                *(uint4*)((char*)vs4 + lof0) = pf0;
                *(uint4*)((char*)vs4 + lof1) = pf1;
                *(uint4*)((char*)vs4 + lof2) = pf2;
                if (gof3 >= 0) *(uint4*)((char*)vs4 + lof3) = pf3;
            }
            if (cl < 2) {
                const __half* xcn = xs + ((size_t)b * 4 + cl + 2) * (size_t)CSTRIDE;
                pf0 = *(const uint4*)(xcn + gof0);
                pf1 = *(const uint4*)(xcn + gof1);
                pf2 = *(const uint4*)(xcn + gof2);
                if (gof3 >= 0) pf3 = *(const uint4*)(xcn + gof3);
            }
        } else {
            if (cl < 3) stageF(cl + 1);
        }

        // ---- Phase C: D-window, 6 outputs per thread (ho,wo,dq) ----
        if (actC) {
            float b0[12], b1[12], b2[12];
#pragma unroll
            for (int k = 0; k < 6; k++) {
                const uint4 vv = sb4[slotC + k];
                float2 f;
                f = __half22float2(u2h(vv.x)); b0[2 * k] = f.x; b0[2 * k + 1] = f.y;
                f = __half22float2(u2h(vv.y)); b1[2 * k] = f.x; b1[2 * k + 1] = f.y;
                f = __half22float2(u2h(vv.z)); b2[2 * k] = f.x; b2[2 * k + 1] = f.y;
            }
            float s0 = 0.f, s1 = 0.f, s2 = 0.f;
#pragma unroll
            for (int k = 0; k < WINS; k++) { s0 += b0[k]; s1 += b1[k]; s2 += b2[k]; }
            const int od0 = 6 * dqC;
#pragma unroll
            for (int k = 0; k < 6; k++) {
                if (k > 0) {
                    s0 += b0[k + 6] - b0[k - 1];
                    s1 += b1[k + 6] - b1[k - 1];
                    s2 += b2[k + 6] - b2[k - 1];
                }
                if (od0 + k < odmax) lsum += sval(s0, s1, s2);
            }
        }
        // no barrier: next iteration's bar1 orders sb reuse & vs reads
    }

    // wave(64) shuffle reduce, then cross-wave via LDS, one atomic per block
#pragma unroll
    for (int off = 32; off > 0; off >>= 1) lsum += __shfl_down(lsum, off, 64);
    const int wave = t >> 6;
    if ((t & 63) == 0) wsum[wave] = lsum;
    __syncthreads();
    if (t == 0) {
        const float s = wsum[0] + wsum[1] + wsum[2] + wsum[3];
        atomicAdd(acc, (double)s);
    }
}

__global__ void structure_loss_finalize(const double* __restrict__ acc,
                                        float* __restrict__ out) {
    out[0] = 1.0f - (float)(acc[0] / 17075520.0);   // 8*154*154*90
}

extern "C" void kernel_launch(void* const* d_in, const int* in_sizes, int n_in,
                              void* d_out, int out_size, void* d_ws, size_t ws_size,
                              hipStream_t stream) {
    const float* x = (const float*)d_in[0];
    const int*   y = (const int*)d_in[1];
    double* acc = (double*)d_ws;
    __half* xs = (__half*)((char*)d_ws + 16);

    const size_t need = 16 + (size_t)8 * CSTRIDE * sizeof(__half);   // ~39.3 MB
    dim3 grid(DTILES, WTILES, 2 * HTILES);   // (4, 20, 40) = 3,200 blocks

    if (ws_size >= need) {
        // prepass zeroes acc -> 3 dispatches total
        sigmoid_prepass<<<dim3(2400, 2), 256, 0, stream>>>(x, y, xs, acc);
        structure_loss_main<true><<<grid, 256, 0, stream>>>(x, y, xs, acc);
    } else {
        (void)hipMemsetAsync(d_ws, 0, sizeof(double), stream);
        structure_loss_main<false><<<grid, 256, 0, stream>>>(x, y, xs, acc);
    }
    structure_loss_finalize<<<1, 1, 0, stream>>>(acc, (float*)d_out);
}

// Round 8
// 186.880 us; speedup vs baseline: 1.0171x; 1.0171x over previous
//
#include <hip/hip_runtime.h>
#include <hip/hip_fp16.h>

// Problem geometry (fixed by reference)
#define WINS 7
#define H 160
#define W 160
#define DD 96
#define HO 154          // H - WINS + 1
#define WO 154
#define DOUT 90
#define CSTRIDE (H*W*DD)   // per-(b,c) channel stride

// Tile: 8x8x24 outputs, all 4 classes sequentially per block.
#define TH 8
#define TW 8
#define TD 24
#define IH 14            // TH + WINS - 1
#define IW 14
#define NCOL (IH * IW)   // 196
#define IDS 32           // staged halfs per column (fallback path only)
#define NDP 15           // dd-pairs per column
#define SAS 30           // sA dd-stride in halfs; layout [ih][wo][dd] (R5)
#define SBC 49           // sb col stride in half2 units (R5)
#define HTILES 20
#define WTILES 20
#define DTILES 4

// R8: no vs staging. Phase A reads its 14 half2 window values DIRECTLY from
// global xs -- each staged element was consumed exactly once (zero reuse),
// so LDS staging was pure overhead (coalescing only). R5 A-map (ih=t/15,
// dp=t%15) makes 15-lane runs contiguous 60B -> coalesced; L1/L2 serve the
// ~3x cross-block halo re-reads (per-block working set ~12-25KB).
// Removes: staging phase, A ds_reads, prefetch regs, swizzle, and 2
// barriers/class. Remaining order needs = 2 barriers/class:
//   barA (after A): sA ready for B; also separates C(cl-1) sb-reads from
//                   B(cl) sb-writes.
//   barB (after B): sb ready for C; also separates B sA-reads from A(cl+1)
//                   sA-writes.
// B and C are byte-identical to the 60us R5 kernel.
// LDS (PRE): sA 20,160 + sb 12,556 + wsum 16 = 32,736 -> 32,768
// -> 5 blocks/CU cap retained (R7 proved the cap drives issue rate).

struct alignas(8) Half4 { __half x, y, z, w; };

static __device__ __forceinline__ __half2 u2h(unsigned int a) {
    __half2 r; __builtin_memcpy(&r, &a, 4); return r;
}
static __device__ __forceinline__ unsigned int h2u(__half2 v) {
    unsigned int r; __builtin_memcpy(&r, &v, 4); return r;
}
// p = max(v,0) per half; m = (sign clear) ? 1.0h : 0.0h per half.
static __device__ __forceinline__ void pmask(__half2 v, __half2& p, __half2& m) {
    const unsigned int bits = h2u(v);
    const unsigned int neg  = bits & 0x80008000u;
    const unsigned int full = (neg >> 15) * 0xFFFFu;          // 0xFFFF where negative
    p = u2h(bits & ~full);
    m = u2h(((~bits >> 15) & 0x00010001u) * 0x3C00u);         // 1.0h where sign clear
}

__device__ __forceinline__ float sval(float c0, float c1, float c2) {
    // c0=S_m, c1=S_tm, c2=S_t2m over the 343-voxel window; t = m?sigmoid:0.5
    const float S_t  = c1 + 0.5f  * (343.0f - c0);
    const float S_t2 = c2 + 0.25f * (343.0f - c0);
    const float inv  = 1.0f / 343.0f;
    const float ux   = S_t  * inv;
    const float uy   = c0   * inv;
    const float uxx  = S_t2 * inv;
    const float uxy  = c1   * inv;
    const float covn = 49.0f / 48.0f;   // WIN^2/(WIN^2-1)
    const float cc   = 0.00045f;        // (0.03*data_range)^2/2, data_range==1
    const float vx  = covn * (uxx - ux * ux);
    const float vy  = covn * (uy  - uy * uy);
    const float vxy = covn * (uxy - ux * uy);
    return (vxy + cc) * __builtin_amdgcn_rcpf(vx * vy + cc);   // den >= ~3e-4
}

// Pre-pass: v = (y==c ? +sigmoid(x) : -sigmoid(x)) as f16, one value per
// (channel, voxel). Also zeroes acc (replaces the hipMemsetAsync dispatch).
__global__ __launch_bounds__(256)
void sigmoid_prepass(const float* __restrict__ x,
                     const int* __restrict__ y,
                     __half* __restrict__ xs,
                     double* __restrict__ acc) {
    if (blockIdx.x == 0 && blockIdx.y == 0 && threadIdx.x == 0) acc[0] = 0.0;
    const int b  = blockIdx.y;
    const int qv = blockIdx.x * 256 + threadIdx.x;    // 0..614399
    const int off = 4 * qv;
    const int4 yv = *(const int4*)(y + (size_t)b * CSTRIDE + off);
#pragma unroll
    for (int c = 0; c < 4; c++) {
        const size_t xo = ((size_t)(b * 4 + c)) * CSTRIDE + off;
        const float4 xv = *(const float4*)(x + xo);
        const float s0 = 1.0f / (1.0f + __expf(-xv.x));
        const float s1 = 1.0f / (1.0f + __expf(-xv.y));
        const float s2 = 1.0f / (1.0f + __expf(-xv.z));
        const float s3 = 1.0f / (1.0f + __expf(-xv.w));
        Half4 hv;
        hv.x = __float2half((yv.x == c) ? s0 : -s0);
        hv.y = __float2half((yv.y == c) ? s1 : -s1);
        hv.z = __float2half((yv.z == c) ? s2 : -s2);
        hv.w = __float2half((yv.w == c) ? s3 : -s3);
        *(Half4*)(xs + xo) = hv;
    }
}

// (256,5): 5-block/CU LDS cap (R7 proved residency drives issue rate).
template <bool PRE>
__global__ __launch_bounds__(256, 5)
void structure_loss_main(const float* __restrict__ x,
                         const int* __restrict__ y,
                         const __half* __restrict__ xs,
                         double* __restrict__ acc) {
    // W-window sums, f16 SoA planes [ih][wo][dd]: 3 * 14*8*30*2 = 20,160 B
    __shared__ __half sA0[IH * TW * SAS];
    __shared__ __half sA1[IH * TW * SAS];
    __shared__ __half sA2[IH * TW * SAS];
    // H-window sums [col][pair][plane] interleaved, col stride SBC: 12,556 B
    __shared__ __half2 sb2[64 * SBC + 3];
    // fallback-only staging (PRE: degenerate size)
    __shared__ __half vsF[PRE ? 2 : NCOL * IDS];
    __shared__ unsigned int yb[PRE ? 1 : NCOL * 2];
    __shared__ float wsum[4];

    const int dt = blockIdx.x;                 // 0..3
    const int wt = blockIdx.y;                 // 0..19
    const int z  = blockIdx.z;                 // 0..39 = b*HTILES + ht
    const int b  = z / HTILES;
    const int ht = z - b * HTILES;

    const int h0 = ht * TH, w0 = wt * TW;
    const int d0 = dt * TD;                          // output base: 0,24,48,72
    const int dstage = (dt == DTILES - 1) ? 64 : d0; // staged window base
    const int doff = d0 - dstage;                    // 0 or 8 (uniform)
    const int odmax = min(TD, DOUT - d0);            // 24,24,24,18
    const int* yc = y + (size_t)b * (size_t)CSTRIDE;
    const int t = threadIdx.x;

    // ---- Hoisted role math ----
    // A role (R5 map: 15-lane contiguous dp runs -> coalesced global reads)
    const bool actA = (t < IH * NDP);          // 210
    const int  ihA  = t / NDP, dpA = t - ihA * NDP;
    const int  sA_  = min(doff + 2 * dpA, IDS - 2);      // <= 30
    const int  hA   = min(h0 + ihA, H - 1);
    const int  wmax = min(IW - 1, W - 1 - w0);           // 13 (7 at wt=19)
    const int  gb0  = (hA * W + w0) * DD + dstage + sA_; // < CSTRIDE-1
    int goff[IW];
#pragma unroll
    for (int iw = 0; iw < IW; iw++) goff[iw] = gb0 + min(iw, wmax) * DD;
    const int  oA0  = (ihA * TW) * SAS + 2 * dpA;
    // B role (R5 exact)
    const bool actB = (t < 2 * TW * NDP);      // 240
    const int  rB   = t / NDP, dpB = t - rB * NDP;
    const int  woB  = rB & 7, ho0B = (rB >> 3) * 4;      // 0 or 4
    const int  idxB0 = (ho0B * TW + woB) * SAS + 2 * dpB;    // k-stride 240
    const int  oB0   = (ho0B * TW + woB) * SBC + dpB * 3;
    // C role (R5 exact)
    const int  dqC  = t & 3, woC = (t >> 2) & 7, hoC = t >> 5;
    const bool actC = (h0 + hoC < HO) && (w0 + woC < WO);
    const int  base2C = (hoC * TW + woC) * SBC + 9 * dqC;

    // ---- Fallback staging lambda (plain vsF layout; perf irrelevant) ----
    auto stageF = [&](int cc) {
        const float* xc = x + ((size_t)b * 4 + cc) * (size_t)CSTRIDE;
#pragma unroll
        for (int k = 0; k < 7; k++) {
            const int i = t + 256 * k;
            if (i < NCOL * 8) {
                const int col = i >> 3, q = i & 7;
                const int ih = col / IW, iw = col - ih * IW;
                const int h = min(h0 + ih, H - 1);
                const int w = min(w0 + iw, W - 1);
                const int dbase = dstage + 4 * q;   // always in-bounds
                const float4 xv = *(const float4*)(xc + (h * W + w) * DD + dbase);
                const unsigned int pk = yb[col * 2 + (q >> 2)] >> (8 * (q & 3));
                const float s0 = 1.0f / (1.0f + __expf(-xv.x));
                const float s1 = 1.0f / (1.0f + __expf(-xv.y));
                const float s2 = 1.0f / (1.0f + __expf(-xv.z));
                const float s3 = 1.0f / (1.0f + __expf(-xv.w));
                Half4 hv;
                hv.x = __float2half(((int)((pk >> 0) & 3u) == cc) ? s0 : -s0);
                hv.y = __float2half(((int)((pk >> 2) & 3u) == cc) ? s1 : -s1);
                hv.z = __float2half(((int)((pk >> 4) & 3u) == cc) ? s2 : -s2);
                hv.w = __float2half(((int)((pk >> 6) & 3u) == cc) ? s3 : -s3);
                *(Half4*)&vsF[col * IDS + 4 * q] = hv;
            }
        }
    };

    if (!PRE) {
        // ---- stage y tile 2-bit packed (fallback only) ----
        for (int i = t; i < NCOL * 2; i += 256) {
            const int col = i >> 1, hf = i & 1;
            const int ih = col / IW, iw = col - ih * IW;
            const int h = min(h0 + ih, H - 1);
            const int w = min(w0 + iw, W - 1);
            const size_t cb = (size_t)(h * W + w) * DD;
            const int dstart = dstage + 16 * hf;     // always in-bounds (<=80)
            unsigned int pk = 0u;
#pragma unroll
            for (int j3 = 0; j3 < 4; j3++) {
                const int4 yv = *(const int4*)(yc + cb + dstart + 4 * j3);
                pk |= (unsigned)(yv.x & 3) << (2 * (4 * j3 + 0));
                pk |= (unsigned)(yv.y & 3) << (2 * (4 * j3 + 1));
                pk |= (unsigned)(yv.z & 3) << (2 * (4 * j3 + 2));
                pk |= (unsigned)(yv.w & 3) << (2 * (4 * j3 + 3));
            }
            yb[i] = pk;
        }
        __syncthreads();
    }

    float lsum = 0.f;

    for (int cl = 0; cl < 4; cl++) {
        if (!PRE) {
            stageF(cl);
            __syncthreads();   // vsF(cl) ready (fallback only)
        }

        // ---- Phase A: direct-global W-window. 210 items (ih,dp) ----
        if (actA) {
            __half2 v2[IW];
            if (PRE) {
                const __half* xcl = xs + (size_t)(4 * b + cl) * (size_t)CSTRIDE;
#pragma unroll
                for (int iw = 0; iw < IW; iw++)
                    v2[iw] = *(const __half2*)(xcl + goff[iw]);
            } else {
#pragma unroll
                for (int iw = 0; iw < IW; iw++)
                    v2[iw] = *(const __half2*)&vsF[(ihA * IW + iw) * IDS + sA_];
            }
            const __half2 z2 = __float2half2_rn(0.f);
            __half2 sm = z2, sp = z2, sq = z2;
#pragma unroll
            for (int iw = 0; iw < WINS; iw++) {
                __half2 p, m;
                pmask(v2[iw], p, m);
                sm = __hadd2(sm, m);
                sp = __hadd2(sp, p);
                sq = __hfma2(p, v2[iw], sq);
            }
            int o = oA0;
            *(__half2*)&sA0[o] = sm;
            *(__half2*)&sA1[o] = sp;
            *(__half2*)&sA2[o] = sq;
#pragma unroll
            for (int wo = 1; wo < TW; wo++) {
                const __half2 a = v2[wo + 6], bb = v2[wo - 1];
                __half2 pa, ma, pb, mb;
                pmask(a, pa, ma);
                pmask(bb, pb, mb);
                sm = __hadd2(sm, __hsub2(ma, mb));
                sp = __hadd2(sp, __hsub2(pa, pb));
                sq = __hadd2(sq, __hsub2(__hmul2(pa, a), __hmul2(pb, bb)));
                o += SAS;
                *(__half2*)&sA0[o] = sm;
                *(__half2*)&sA1[o] = sp;
                *(__half2*)&sA2[o] = sq;
            }
        }
        __syncthreads();   // barA: sA ready; C(cl-1) sb-reads retired

        // ---- Phase B: H-window (R5 exact). 240 items ----
        if (actB) {
            __half2 a0[10], a1[10], a2[10];
#pragma unroll
            for (int k = 0; k < 10; k++) {
                const int idx = idxB0 + k * (TW * SAS);
                a0[k] = *(const __half2*)&sA0[idx];
                a1[k] = *(const __half2*)&sA1[idx];
                a2[k] = *(const __half2*)&sA2[idx];
            }
            __half2 s0 = a0[0], s1 = a1[0], s2 = a2[0];
#pragma unroll
            for (int k = 1; k < WINS; k++) {
                s0 = __hadd2(s0, a0[k]);
                s1 = __hadd2(s1, a1[k]);
                s2 = __hadd2(s2, a2[k]);
            }
            int o = oB0;
            sb2[o] = s0; sb2[o + 1] = s1; sb2[o + 2] = s2;
#pragma unroll
            for (int k = 1; k < 4; k++) {
                s0 = __hadd2(s0, __hsub2(a0[k + 6], a0[k - 1]));
                s1 = __hadd2(s1, __hsub2(a1[k + 6], a1[k - 1]));
                s2 = __hadd2(s2, __hsub2(a2[k + 6], a2[k - 1]));
                o += TW * SBC;
                sb2[o] = s0; sb2[o + 1] = s1; sb2[o + 2] = s2;
            }
        }
        __syncthreads();   // barB: sb ready; B sA-reads retired before next A

        // ---- Phase C: D-window, 6 outputs per thread (R5 exact) ----
        if (actC) {
            float b0[12], b1[12], b2[12];
#pragma unroll
            for (int k = 0; k < 6; k++) {
                float2 f;
                f = __half22float2(sb2[base2C + 3 * k + 0]);
                b0[2 * k] = f.x; b0[2 * k + 1] = f.y;
                f = __half22float2(sb2[base2C + 3 * k + 1]);
                b1[2 * k] = f.x; b1[2 * k + 1] = f.y;
                f = __half22float2(sb2[base2C + 3 * k + 2]);
                b2[2 * k] = f.x; b2[2 * k + 1] = f.y;
            }
            float s0 = 0.f, s1 = 0.f, s2 = 0.f;
#pragma unroll
            for (int k = 0; k < WINS; k++) { s0 += b0[k]; s1 += b1[k]; s2 += b2[k]; }
            const int od0 = 6 * dqC;
#pragma unroll
            for (int k = 0; k < 6; k++) {
                if (k > 0) {
                    s0 += b0[k + 6] - b0[k - 1];
                    s1 += b1[k + 6] - b1[k - 1];
                    s2 += b2[k + 6] - b2[k - 1];
                }
                if (od0 + k < odmax) lsum += sval(s0, s1, s2);
            }
        }
        // no trailing barrier: next barA separates C's sb-reads from B(cl+1)
    }

    // wave(64) shuffle reduce, then cross-wave via LDS, one atomic per block
#pragma unroll
    for (int off = 32; off > 0; off >>= 1) lsum += __shfl_down(lsum, off, 64);
    const int wave = t >> 6;
    if ((t & 63) == 0) wsum[wave] = lsum;
    __syncthreads();
    if (t == 0) {
        const float s = wsum[0] + wsum[1] + wsum[2] + wsum[3];
        atomicAdd(acc, (double)s);
    }
}

__global__ void structure_loss_finalize(const double* __restrict__ acc,
                                        float* __restrict__ out) {
    out[0] = 1.0f - (float)(acc[0] / 17075520.0);   // 8*154*154*90
}

extern "C" void kernel_launch(void* const* d_in, const int* in_sizes, int n_in,
                              void* d_out, int out_size, void* d_ws, size_t ws_size,
                              hipStream_t stream) {
    const float* x = (const float*)d_in[0];
    const int*   y = (const int*)d_in[1];
    double* acc = (double*)d_ws;
    __half* xs = (__half*)((char*)d_ws + 16);

    const size_t need = 16 + (size_t)8 * CSTRIDE * sizeof(__half);   // ~39.3 MB
    dim3 grid(DTILES, WTILES, 2 * HTILES);   // (4, 20, 40) = 3,200 blocks

    if (ws_size >= need) {
        // prepass zeroes acc -> 3 dispatches total
        sigmoid_prepass<<<dim3(2400, 2), 256, 0, stream>>>(x, y, xs, acc);
        structure_loss_main<true><<<grid, 256, 0, stream>>>(x, y, xs, acc);
    } else {
        (void)hipMemsetAsync(d_ws, 0, sizeof(double), stream);
        structure_loss_main<false><<<grid, 256, 0, stream>>>(x, y, xs, acc);
    }
    structure_loss_finalize<<<1, 1, 0, stream>>>(acc, (float*)d_out);
}